// Round 2
// baseline (462.157 us; speedup 1.0000x reference)
//
#include <hip/hip_runtime.h>

#define NN 100000
#define EE 1600000
#define D 128
#define NPART 8                   // dst-space partitions
#define PSZ (NN / NPART)          // 12500 nodes per partition
#define NI4 (EE / 4)              // 400000 int4 records in dst/src
#define SUBW 196                  // dst nodes per sub-bucket (64 per partition)
#define NSB (NPART * 64)          // 512 sub-buckets
#define SCAP 4096                 // records per sub-bucket (exp 3136, +17 sigma)
#define RCAP 8192                 // csr slots per sub-bucket region (exp ~3960)
#define LBCAP 96                  // LDS bin capacity (exp 49, +6.7 sigma; overflow ok)

typedef __attribute__((ext_vector_type(8))) short bf16x8;
typedef __attribute__((ext_vector_type(4))) float f32x4;

// bf16 helpers (exact unpack; RN pack)
__device__ inline unsigned int f2bf2(float a, float b) {  // pack (a=low, b=high)
    unsigned int ua = __float_as_uint(a);
    unsigned int ub = __float_as_uint(b);
    ua = (ua + 0x7fffu + ((ua >> 16) & 1u)) >> 16;
    ub = (ub + 0x7fffu + ((ub >> 16) & 1u)) >> 16;
    return ua | (ub << 16);
}
__device__ inline unsigned short f2bf(float a) {
    unsigned int u = __float_as_uint(a);
    return (unsigned short)((u + 0x7fffu + ((u >> 16) & 1u)) >> 16);
}
__device__ inline float2 bf2f2(unsigned int u) {
    return make_float2(__uint_as_float(u << 16), __uint_as_float(u & 0xffff0000u));
}

// ---------------- graph prep ----------------

// zero sub-bucket cursors + sentinel xs rows (index NN) in both ping buffers
__global__ void init_kernel(int* __restrict__ gcur2, unsigned int* __restrict__ xsA,
                            unsigned int* __restrict__ xsB) {
    int i = blockIdx.x * blockDim.x + threadIdx.x;
    if (i < NSB) gcur2[i] = 0;
    if (i < 64) {
        xsA[(size_t)NN * 64 + i] = 0;
        xsB[(size_t)NN * 64 + i] = 0;
    }
}

// phase 1: partition-filter + LDS bin into 64 sub-buckets per partition.
__global__ __launch_bounds__(256) void filterbin_kernel(const int4* __restrict__ src4,
                                                        const int4* __restrict__ dst4,
                                                        int* __restrict__ gcur2,
                                                        uint2* __restrict__ buckets2) {
    __shared__ uint2 bins[64][LBCAP];
    __shared__ int bcnt[64];
    __shared__ int gbase[64];
    const int p = blockIdx.x >> 6;
    const int c = blockIdx.x & 63;
    if (threadIdx.x < 64) bcnt[threadIdx.x] = 0;
    __syncthreads();
    const int lo = p * PSZ, hi = lo + PSZ;
    const int chunk4 = NI4 / 64;                    // 6250, exact
    const int a0 = c * chunk4, a1 = a0 + chunk4;
    for (int i = a0 + threadIdx.x; i < a1; i += 256) {
        int4 d4 = dst4[i];
        bool m0 = (d4.x >= lo && d4.x < hi);
        bool m1 = (d4.y >= lo && d4.y < hi);
        bool m2 = (d4.z >= lo && d4.z < hi);
        bool m3 = (d4.w >= lo && d4.w < hi);
        if (!(m0 | m1 | m2 | m3)) continue;
        int4 s4 = src4[i];
        int ss[4] = {s4.x, s4.y, s4.z, s4.w};
        int dd[4] = {d4.x, d4.y, d4.z, d4.w};
        bool mm[4] = {m0, m1, m2, m3};
#pragma unroll
        for (int k = 0; k < 4; ++k) {
            if (!mm[k]) continue;
            int li = (dd[k] - lo) / SUBW;           // 0..63
            int pos = atomicAdd(&bcnt[li], 1);
            if (pos < LBCAP) {
                bins[li][pos] = make_uint2((unsigned)ss[k], (unsigned)dd[k]);
            } else {                                 // rare overflow: direct append
                int sb = p * 64 + li;
                int gp = atomicAdd(&gcur2[sb], 1);
                buckets2[(size_t)sb * SCAP + gp] = make_uint2((unsigned)ss[k], (unsigned)dd[k]);
            }
        }
    }
    __syncthreads();
    if (threadIdx.x < 64) {
        int cc = min(bcnt[threadIdx.x], LBCAP);
        gbase[threadIdx.x] = atomicAdd(&gcur2[p * 64 + threadIdx.x], cc);
        bcnt[threadIdx.x] = cc;
    }
    __syncthreads();
    for (int b = 0; b < 64; ++b) {
        const int cc = bcnt[b];
        uint2* outp = buckets2 + (size_t)(p * 64 + b) * SCAP + gbase[b];
        for (int i = threadIdx.x; i < cc; i += 256) outp[i] = bins[b][i];
    }
}

// phase 2: per sub-bucket LDS counting-sort into padded compact csr rows.
__global__ __launch_bounds__(256) void sort3_kernel(const uint2* __restrict__ buckets2,
                                                    const int* __restrict__ gcur2,
                                                    int* __restrict__ csr,
                                                    int* __restrict__ info,
                                                    float* __restrict__ dinv) {
    __shared__ int hist[256];
    __shared__ int pscan[256];
    __shared__ int lcur[256];
    __shared__ int staged[RCAP];
    const int sb = blockIdx.x;
    const int li = sb & 63;
    const int base_node = (sb >> 6) * PSZ + li * SUBW;
    const int nnodes = min(SUBW, PSZ - li * SUBW);  // 196 (152 for last)
    const int scnt = gcur2[sb];
    const uint2* bk = buckets2 + (size_t)sb * SCAP;
    const int t = threadIdx.x;
    hist[t] = 0;
    __syncthreads();
    for (int i = t; i < scnt; i += 256) atomicAdd(&hist[(int)bk[i].y - base_node], 1);
    __syncthreads();
    const int padded = (t < nnodes) ? ((hist[t] + 7) & ~7) : 0;
    pscan[t] = padded;
    __syncthreads();
    for (int off = 1; off < 256; off <<= 1) {
        int v = (t >= off) ? pscan[t - off] : 0;
        __syncthreads();
        pscan[t] += v;
        __syncthreads();
    }
    const int rstart = pscan[t] - padded;           // exclusive scan
    lcur[t] = rstart;
    __syncthreads();
    const int total = pscan[255];                   // multiple of 8
    for (int i = t; i < total; i += 256) staged[i] = NN;  // sentinel fill
    __syncthreads();
    for (int i = t; i < scnt; i += 256) {
        uint2 r = bk[i];
        int pos = atomicAdd(&lcur[(int)r.y - base_node], 1);
        staged[pos] = (int)r.x;
    }
    __syncthreads();
    int4* co = (int4*)(csr + (size_t)sb * RCAP);
    for (int i = t; i < (total >> 2); i += 256) co[i] = ((const int4*)staged)[i];
    if (t < nnodes) {
        int dg = hist[t];
        info[base_node + t] = ((sb * RCAP + rstart) << 8) | dg;   // rowoff<24b, deg<8b
        dinv[base_node + t] = rsqrtf(1.0f + (float)dg);
    }
}

// W[k][n] fp32 -> Wt[n][k] bf16, all three weights in one launch (192 blocks)
__global__ void wt_build3_kernel(const float* __restrict__ W1, const float* __restrict__ W2,
                                 const float* __restrict__ W3, unsigned short* __restrict__ wt1,
                                 unsigned short* __restrict__ wt2, unsigned short* __restrict__ wt3) {
    const int which = blockIdx.x >> 6;
    const float* W = which == 0 ? W1 : (which == 1 ? W2 : W3);
    unsigned short* wt = which == 0 ? wt1 : (which == 1 ? wt2 : wt3);
    int i = (blockIdx.x & 63) * 256 + threadIdx.x;
    int n = i >> 7, k = i & 127;
    wt[n * 128 + k] = f2bf(W[k * 128 + n]);
}

// xs0[s] = bf16( dinv[s] * x0[s] )  -- layer-1 input, pre-scaled for aggregate-first
__global__ __launch_bounds__(256) void scale0_kernel(const float* __restrict__ x0,
                                                     const float* __restrict__ dinv,
                                                     unsigned int* __restrict__ xs) {
    int i = blockIdx.x * 256 + threadIdx.x;     // 0 .. NN*32, exact
    int row = i >> 5, c = (i & 31) * 4;         // 4 float cols per thread
    float4 v = *(const float4*)(x0 + (size_t)row * 128 + c);
    float dv = dinv[row];
    *(uint2*)(xs + (size_t)row * 64 + (c >> 1)) =
        make_uint2(f2bf2(v.x * dv, v.y * dv), f2bf2(v.z * dv, v.w * dv));
}

// ---------------- fused layer: aggregate-first + GEMM ------------------------
// out[d] = relu( (dinv[d]*(xs[d] + sum_e xs[src_e])) @ W + b ) [ * dinv[d] if !LAST ]
// Block = 256 thr = 4 waves, owns 64 dst rows. Phase 1: wave w gathers+sums
// nodes base+w*16+i (i=0..15), writes bf16 y-rows to LDS. Phase 2: each wave
// runs the 16x128 MFMA tile (operand swap: A=Wt-frag, B=y-frag -> lane holds
// out[base+w*16+(lane&15)][nt*16+q*4+reg]). y-row LDS stride 68 uints keeps
// ds_read_b128 16B-aligned (272 = 17*16).

template <bool LAST>
__global__ __launch_bounds__(256) void fused_kernel(const unsigned int* __restrict__ xs,
                                                    const unsigned short* __restrict__ wt,
                                                    const int* __restrict__ csr,
                                                    const int* __restrict__ info,
                                                    const float* __restrict__ dinv,
                                                    const float* __restrict__ bias,
                                                    void* __restrict__ outp) {
    __shared__ unsigned int ylds[64 * 68];
    const int w = threadIdx.x >> 6;
    const int j = threadIdx.x & 63;     // lane; owns cols 2j,2j+1 in gather phase
    const int base = blockIdx.x * 64;

    // ---- phase 1: gather + normalize, y rows -> LDS ----
    for (int i = 0; i < 16; ++i) {
        const int d = base + w * 16 + i;
        if (d >= NN) break;             // wave-uniform
        const int ifo = info[d];
        int e = ifo >> 8;
        const int end = e + (((ifo & 255) + 7) & ~7);
        float2 acc = bf2f2(xs[(size_t)d * 64 + j]);   // self term
        for (; e + 16 <= end; e += 16) {
            int4 c0 = *(const int4*)(csr + e);
            int4 c1 = *(const int4*)(csr + e + 4);
            int4 c2 = *(const int4*)(csr + e + 8);
            int4 c3 = *(const int4*)(csr + e + 12);
            unsigned int v0 = xs[(size_t)c0.x * 64 + j];
            unsigned int v1 = xs[(size_t)c0.y * 64 + j];
            unsigned int v2 = xs[(size_t)c0.z * 64 + j];
            unsigned int v3 = xs[(size_t)c0.w * 64 + j];
            unsigned int v4 = xs[(size_t)c1.x * 64 + j];
            unsigned int v5 = xs[(size_t)c1.y * 64 + j];
            unsigned int v6 = xs[(size_t)c1.z * 64 + j];
            unsigned int v7 = xs[(size_t)c1.w * 64 + j];
            unsigned int v8 = xs[(size_t)c2.x * 64 + j];
            unsigned int v9 = xs[(size_t)c2.y * 64 + j];
            unsigned int va = xs[(size_t)c2.z * 64 + j];
            unsigned int vb = xs[(size_t)c2.w * 64 + j];
            unsigned int vc = xs[(size_t)c3.x * 64 + j];
            unsigned int vd = xs[(size_t)c3.y * 64 + j];
            unsigned int ve = xs[(size_t)c3.z * 64 + j];
            unsigned int vf = xs[(size_t)c3.w * 64 + j];
            float2 f0 = bf2f2(v0), f1 = bf2f2(v1), f2 = bf2f2(v2), f3 = bf2f2(v3);
            float2 f4 = bf2f2(v4), f5 = bf2f2(v5), f6 = bf2f2(v6), f7 = bf2f2(v7);
            float2 f8 = bf2f2(v8), f9 = bf2f2(v9), fa = bf2f2(va), fb = bf2f2(vb);
            float2 fc = bf2f2(vc), fd = bf2f2(vd), fe = bf2f2(ve), ff = bf2f2(vf);
            acc.x += ((f0.x + f1.x) + (f2.x + f3.x)) + ((f4.x + f5.x) + (f6.x + f7.x)) +
                     ((f8.x + f9.x) + (fa.x + fb.x)) + ((fc.x + fd.x) + (fe.x + ff.x));
            acc.y += ((f0.y + f1.y) + (f2.y + f3.y)) + ((f4.y + f5.y) + (f6.y + f7.y)) +
                     ((f8.y + f9.y) + (fa.y + fb.y)) + ((fc.y + fd.y) + (fe.y + ff.y));
        }
        if (e < end) {  // one trailing 8-batch
            int4 c0 = *(const int4*)(csr + e);
            int4 c1 = *(const int4*)(csr + e + 4);
            unsigned int v0 = xs[(size_t)c0.x * 64 + j];
            unsigned int v1 = xs[(size_t)c0.y * 64 + j];
            unsigned int v2 = xs[(size_t)c0.z * 64 + j];
            unsigned int v3 = xs[(size_t)c0.w * 64 + j];
            unsigned int v4 = xs[(size_t)c1.x * 64 + j];
            unsigned int v5 = xs[(size_t)c1.y * 64 + j];
            unsigned int v6 = xs[(size_t)c1.z * 64 + j];
            unsigned int v7 = xs[(size_t)c1.w * 64 + j];
            float2 f0 = bf2f2(v0), f1 = bf2f2(v1), f2 = bf2f2(v2), f3 = bf2f2(v3);
            float2 f4 = bf2f2(v4), f5 = bf2f2(v5), f6 = bf2f2(v6), f7 = bf2f2(v7);
            acc.x += ((f0.x + f1.x) + (f2.x + f3.x)) + ((f4.x + f5.x) + (f6.x + f7.x));
            acc.y += ((f0.y + f1.y) + (f2.y + f3.y)) + ((f4.y + f5.y) + (f6.y + f7.y));
        }
        const float dv = dinv[d];
        ylds[(w * 16 + i) * 68 + j] = f2bf2(dv * acc.x, dv * acc.y);
    }
    __syncthreads();

    // ---- phase 2: y @ W via MFMA ----
    const int r = j & 15;
    const int q = j >> 4;
    const unsigned short* wrow = wt + (size_t)r * 128 + q * 8;
    const int myrow = w * 16 + r;
    f32x4 acc[8] = {};
#pragma unroll
    for (int kc = 0; kc < 4; ++kc) {
        bf16x8 xf = *(const bf16x8*)(ylds + myrow * 68 + q * 4 + kc * 16);
#pragma unroll
        for (int nt = 0; nt < 8; ++nt) {
            bf16x8 wf = *(const bf16x8*)(wrow + (size_t)nt * 16 * 128 + kc * 32);
            acc[nt] = __builtin_amdgcn_mfma_f32_16x16x32_bf16(wf, xf, acc[nt], 0, 0, 0);
        }
    }
    const int orow = base + myrow;
    if (orow >= NN) return;
    if (LAST) {
        float* op = (float*)outp + (size_t)orow * 128;
#pragma unroll
        for (int nt = 0; nt < 8; ++nt) {
            int n = nt * 16 + q * 4;
            float4 bb = *(const float4*)(bias + n);
            float4 o;
            o.x = fmaxf(acc[nt][0] + bb.x, 0.0f);
            o.y = fmaxf(acc[nt][1] + bb.y, 0.0f);
            o.z = fmaxf(acc[nt][2] + bb.z, 0.0f);
            o.w = fmaxf(acc[nt][3] + bb.w, 0.0f);
            *(float4*)(op + n) = o;
        }
    } else {
        const float dvr = dinv[orow];   // fold next layer's src-scale into epilogue
        unsigned int* op = (unsigned int*)outp + (size_t)orow * 64;
#pragma unroll
        for (int nt = 0; nt < 8; ++nt) {
            int n = nt * 16 + q * 4;
            float4 bb = *(const float4*)(bias + n);
            float o0 = fmaxf(acc[nt][0] + bb.x, 0.0f) * dvr;
            float o1 = fmaxf(acc[nt][1] + bb.y, 0.0f) * dvr;
            float o2 = fmaxf(acc[nt][2] + bb.z, 0.0f) * dvr;
            float o3 = fmaxf(acc[nt][3] + bb.w, 0.0f) * dvr;
            *(uint2*)(op + (n >> 1)) = make_uint2(f2bf2(o0, o1), f2bf2(o2, o3));
        }
    }
}

// ---------------- launch ----------------

extern "C" void kernel_launch(void* const* d_in, const int* in_sizes, int n_in,
                              void* d_out, int out_size, void* d_ws, size_t ws_size,
                              hipStream_t stream) {
    const float* x0 = (const float*)d_in[0];
    const int* ei = (const int*)d_in[1];   // int32 on device (harness contract)
    const float* W1 = (const float*)d_in[2];
    const float* b1 = (const float*)d_in[3];
    const float* W2 = (const float*)d_in[4];
    const float* b2 = (const float*)d_in[5];
    const float* W3 = (const float*)d_in[6];
    const float* b3 = (const float*)d_in[7];
    float* out = (float*)d_out;

    char* ws = (char*)d_ws;
    size_t off = 0;
    auto alloc = [&](size_t bytes) -> void* {
        off = (off + 511) & ~(size_t)511;
        void* p = ws + off;
        off += bytes;
        return p;
    };
    unsigned int* xsA = (unsigned int*)alloc(((size_t)NN + 1) * 64 * 4);   // 25.6 MB (+ zero row)
    int*   csr     = (int*)  alloc((size_t)NSB * RCAP * sizeof(int));      // 16.8 MB
    uint2* buckets2 = (uint2*)alloc((size_t)NSB * SCAP * sizeof(uint2));   // 16.8 MB
    int*   info    = (int*)  alloc((size_t)NN * sizeof(int));
    float* dinv    = (float*)alloc((size_t)NN * sizeof(float));
    int*   gcur2   = (int*)  alloc(NSB * sizeof(int));
    unsigned short* wt1 = (unsigned short*)alloc(128 * 128 * 2);
    unsigned short* wt2 = (unsigned short*)alloc(128 * 128 * 2);
    unsigned short* wt3 = (unsigned short*)alloc(128 * 128 * 2);

    // ping buffer B lives in d_out's first 25.6 MB (+ sentinel row; dead by layer 3)
    unsigned int* xsB = (unsigned int*)d_out;

    const int4* src4 = (const int4*)ei;          // edge_index[0]
    const int4* dst4 = (const int4*)(ei + EE);   // edge_index[1]

    // graph prep (redone every call: ws is re-poisoned)
    init_kernel<<<2, 256, 0, stream>>>(gcur2, xsA, xsB);
    filterbin_kernel<<<NSB, 256, 0, stream>>>(src4, dst4, gcur2, buckets2);
    sort3_kernel<<<NSB, 256, 0, stream>>>(buckets2, gcur2, csr, info, dinv);
    wt_build3_kernel<<<192, 256, 0, stream>>>(W1, W2, W3, wt1, wt2, wt3);
    scale0_kernel<<<NN * 32 / 256, 256, 0, stream>>>(x0, dinv, xsA);

    const int fusedBlocks = (NN + 63) / 64;      // 1563

    fused_kernel<false><<<fusedBlocks, 256, 0, stream>>>(xsA, wt1, csr, info, dinv, b1, (void*)xsB);
    fused_kernel<false><<<fusedBlocks, 256, 0, stream>>>(xsB, wt2, csr, info, dinv, b2, (void*)xsA);
    fused_kernel<true><<<fusedBlocks, 256, 0, stream>>>(xsA, wt3, csr, info, dinv, b3, (void*)out);
}